// Round 1
// baseline (791.085 us; speedup 1.0000x reference)
//
#include <hip/hip_runtime.h>
#include <math.h>

#define B_   32
#define H_   32
#define HKV  8
#define G_   4
#define D_   128
#define BS_  128
#define NB_  16

// ---------------------------------------------------------------------------
// Kernel 1: insert new decode token K/V into the paged caches.
// B*HKV*D = 32768 elements; grid 64 x 512.
// ---------------------------------------------------------------------------
__global__ __launch_bounds__(512) void scatter_kv(
    const float* __restrict__ knew, const float* __restrict__ vnew,
    float* __restrict__ kcache, float* __restrict__ vcache,
    const int* __restrict__ bidx, const int* __restrict__ boff)
{
    const int gid = blockIdx.x * 512 + threadIdx.x;   // 0..32767
    const int b = gid >> 10;                          // /(HKV*D)
    const int r = gid & 1023;                         // kh*D + d
    const size_t dst = ((size_t)bidx[b] * BS_ + (size_t)boff[b]) * (HKV * D_) + r;
    kcache[dst] = knew[gid];
    vcache[dst] = vnew[gid];
}

// ---------------------------------------------------------------------------
// Kernel 2: flat paged decode attention.
// One workgroup per (b, kv_head): 256 blocks x 512 threads (8 waves).
// Phase A: QK^T scores (+bias) for all 2048 positions -> LDS.
// Phase B: flat softmax (per-g max, exp, denom) in LDS.
// Phase C: P*V accumulate in registers, cross-wave combine, store o/denom.
// ---------------------------------------------------------------------------
__global__ __launch_bounds__(512) void paged_attn(
    const float* __restrict__ query,
    const float* __restrict__ kcache,
    const float* __restrict__ vcache,
    const int* __restrict__ block_list,
    const float* __restrict__ block_bias,
    float* __restrict__ out)
{
    __shared__ float q_s[G_][D_];            // 2 KB
    __shared__ float sc[NB_ * BS_ * G_];     // 32 KB, layout [pos][g]
    __shared__ float red[8][G_];             // per-wave reduce scratch
    __shared__ float mg[G_];                 // per-g global max
    __shared__ float den[G_];                // per-g denominator
    __shared__ float owb[8][G_][D_];         // 16 KB, per-wave o partials

    const int tid  = threadIdx.x;
    const int w    = tid >> 6;
    const int lane = tid & 63;
    const int b    = blockIdx.x >> 3;
    const int kh   = blockIdx.x & 7;
    constexpr float SCALE = 0.08838834764831845f;  // 1/sqrt(128)

    // ---- load scaled query (4 GQA heads for this kv head) ----
    for (int i = tid; i < G_ * D_; i += 512) {
        const int g = i >> 7, d = i & 127;
        q_s[g][d] = query[(size_t)b * (H_ * D_) + (size_t)(kh * G_ + g) * D_ + d] * SCALE;
    }
    __syncthreads();

    // each lane owns dims {2*lane, 2*lane+1}
    const float q0x = q_s[0][2*lane], q0y = q_s[0][2*lane+1];
    const float q1x = q_s[1][2*lane], q1y = q_s[1][2*lane+1];
    const float q2x = q_s[2][2*lane], q2y = q_s[2][2*lane+1];
    const float q3x = q_s[3][2*lane], q3y = q_s[3][2*lane+1];

    // ---- Phase A: scores ----
    for (int j = 0; j < NB_; ++j) {
        const int tb = b * NB_ + j;
        const int cb = block_list[tb];
        const float* kb   = kcache + ((size_t)cb * BS_ * HKV + kh) * D_;
        const float* brow = block_bias + (size_t)tb * BS_;
#pragma unroll
        for (int k = 0; k < 16; ++k) {
            const int s = w * 16 + k;   // wave w owns rows [16w, 16w+16)
            const float2 kv = *(const float2*)(kb + (size_t)s * (HKV * D_) + 2 * lane);
            float d0 = q0x * kv.x + q0y * kv.y;
            float d1 = q1x * kv.x + q1y * kv.y;
            float d2 = q2x * kv.x + q2y * kv.y;
            float d3 = q3x * kv.x + q3y * kv.y;
#pragma unroll
            for (int m = 32; m >= 1; m >>= 1) {
                d0 += __shfl_xor(d0, m, 64);
                d1 += __shfl_xor(d1, m, 64);
                d2 += __shfl_xor(d2, m, 64);
                d3 += __shfl_xor(d3, m, 64);
            }
            if (lane == 0) {
                const float bv = brow[s];
                const int p4 = (j * BS_ + s) * G_;
                sc[p4 + 0] = d0 + bv;
                sc[p4 + 1] = d1 + bv;
                sc[p4 + 2] = d2 + bv;
                sc[p4 + 3] = d3 + bv;
            }
        }
    }
    __syncthreads();

    // ---- Phase B: flat softmax over 2048 positions, per g ----
    {
        const int g = tid & 3;
        const int u = tid >> 2;           // 0..127
        float m = -INFINITY;
#pragma unroll
        for (int i = 0; i < 16; ++i)
            m = fmaxf(m, sc[(u + 128 * i) * G_ + g]);
        // reduce across lanes sharing the same g (bits 2..5 of lane)
#pragma unroll
        for (int msk = 4; msk <= 32; msk <<= 1)
            m = fmaxf(m, __shfl_xor(m, msk, 64));
        if (lane < 4) red[w][lane] = m;
        __syncthreads();
        if (tid < 4) {
            float mm = red[0][tid];
            for (int ww = 1; ww < 8; ++ww) mm = fmaxf(mm, red[ww][tid]);
            mg[tid] = mm;
        }
        __syncthreads();

        const float gm = mg[g];
        float acc = 0.f;
#pragma unroll
        for (int i = 0; i < 16; ++i) {
            const int idx = (u + 128 * i) * G_ + g;
            const float p = __expf(sc[idx] - gm);   // exp(-inf)=0 handles mask
            sc[idx] = p;
            acc += p;
        }
#pragma unroll
        for (int msk = 4; msk <= 32; msk <<= 1)
            acc += __shfl_xor(acc, msk, 64);
        if (lane < 4) red[w][lane] = acc;
        __syncthreads();
        if (tid < 4) {
            float ss = 0.f;
            for (int ww = 0; ww < 8; ++ww) ss += red[ww][tid];
            den[tid] = ss;
        }
        __syncthreads();
    }

    // ---- Phase C: P*V ----
    float o0x = 0.f, o0y = 0.f, o1x = 0.f, o1y = 0.f;
    float o2x = 0.f, o2y = 0.f, o3x = 0.f, o3y = 0.f;
    for (int j = 0; j < NB_; ++j) {
        const int cb = block_list[b * NB_ + j];
        const float* vb = vcache + ((size_t)cb * BS_ * HKV + kh) * D_;
#pragma unroll
        for (int k = 0; k < 16; ++k) {
            const int s = w * 16 + k;
            const float4 p = *(const float4*)&sc[(j * BS_ + s) * G_];  // broadcast
            const float2 vv = *(const float2*)(vb + (size_t)s * (HKV * D_) + 2 * lane);
            o0x += p.x * vv.x; o0y += p.x * vv.y;
            o1x += p.y * vv.x; o1y += p.y * vv.y;
            o2x += p.z * vv.x; o2y += p.z * vv.y;
            o3x += p.w * vv.x; o3y += p.w * vv.y;
        }
    }
    owb[w][0][2*lane] = o0x; owb[w][0][2*lane+1] = o0y;
    owb[w][1][2*lane] = o1x; owb[w][1][2*lane+1] = o1y;
    owb[w][2][2*lane] = o2x; owb[w][2][2*lane+1] = o2y;
    owb[w][3][2*lane] = o3x; owb[w][3][2*lane+1] = o3y;
    __syncthreads();

    // ---- combine across waves + normalize + store ----
    {
        const int ge = tid >> 7, de = tid & 127;   // 512 threads -> 4x128 elems
        float s = 0.f;
        for (int ww = 0; ww < 8; ++ww) s += owb[ww][ge][de];
        out[(size_t)b * (H_ * D_) + (size_t)(kh * G_ + ge) * D_ + de] = s / den[ge];
    }
}

extern "C" void kernel_launch(void* const* d_in, const int* in_sizes, int n_in,
                              void* d_out, int out_size, void* d_ws, size_t ws_size,
                              hipStream_t stream) {
    const float* query = (const float*)d_in[0];
    const float* knew  = (const float*)d_in[1];
    const float* vnew  = (const float*)d_in[2];
    float* kcache      = (float*)d_in[3];
    float* vcache      = (float*)d_in[4];
    const int* block_list = (const int*)d_in[5];
    // d_in[6] block_groups: structure is t/NB (fixed harness input), unused
    const int* bidx = (const int*)d_in[7];
    const int* boff = (const int*)d_in[8];
    const float* bias = (const float*)d_in[9];
    float* out = (float*)d_out;

    hipLaunchKernelGGL(scatter_kv, dim3(64), dim3(512), 0, stream,
                       knew, vnew, kcache, vcache, bidx, boff);
    hipLaunchKernelGGL(paged_attn, dim3(256), dim3(512), 0, stream,
                       query, kcache, vcache, block_list, bias, out);
}

// Round 2
// 591.777 us; speedup vs baseline: 1.3368x; 1.3368x over previous
//
#include <hip/hip_runtime.h>
#include <math.h>

#define B_   32
#define H_   32
#define HKV  8
#define G_   4
#define D_   128
#define BS_  128
#define NB_  16
#define CH_  2             // cache blocks per chunk
#define NCH  (NB_ / CH_)   // 8 chunks per sequence
#define CP_  (CH_ * BS_)   // 256 positions per chunk
#define PART_STRIDE (G_ + G_ + G_ * D_)   // m[4] l[4] o[4][128] = 520 floats

// ---------------------------------------------------------------------------
// Kernel 1: insert new decode token K/V into the paged caches.
// ---------------------------------------------------------------------------
__global__ __launch_bounds__(512) void scatter_kv(
    const float* __restrict__ knew, const float* __restrict__ vnew,
    float* __restrict__ kcache, float* __restrict__ vcache,
    const int* __restrict__ bidx, const int* __restrict__ boff)
{
    const int gid = blockIdx.x * 512 + threadIdx.x;   // 0..32767
    const int b = gid >> 10;
    const int r = gid & 1023;
    const size_t dst = ((size_t)bidx[b] * BS_ + (size_t)boff[b]) * (HKV * D_) + r;
    kcache[dst] = knew[gid];
    vcache[dst] = vnew[gid];
}

// ---------------------------------------------------------------------------
// Kernel 2: partial attention over one chunk (2 cache blocks = 256 positions)
// of one (b, kv_head). Grid 2048 = B*HKV*NCH, 256 threads (4 waves).
// Writes partial (m[4], l[4], o[4][128]) to workspace.
// Row mapping: wave w owns chunk positions [64w, 64w+64); within a float4
// instruction lanes 0-31 cover row p (512B) and lanes 32-63 row p+1.
// ---------------------------------------------------------------------------
__global__ __launch_bounds__(256) void partial_attn(
    const float* __restrict__ query,
    const float* __restrict__ kcache,
    const float* __restrict__ vcache,
    const int* __restrict__ block_list,
    const float* __restrict__ block_bias,
    float* __restrict__ ws)
{
    __shared__ float q_s[G_][D_];        // 2 KB
    __shared__ float sc[CP_][G_];        // 4 KB scores -> p
    __shared__ float red[4][G_];
    __shared__ float mg[G_];             // true chunk max (may be -inf)
    __shared__ float dn[G_];             // chunk denom partial
    __shared__ float ob[4][G_][D_];      // 8 KB per-wave o partials

    const int tid  = threadIdx.x;
    const int w    = tid >> 6;
    const int lane = tid & 63;
    const int half = lane >> 5;          // 0: row 2i, 1: row 2i+1
    const int l5   = lane & 31;
    const int dd   = l5 * 4;             // dims owned by this lane
    const int bx   = blockIdx.x;
    const int ch   = bx & (NCH - 1);
    const int kh   = (bx >> 3) & 7;
    const int b    = bx >> 6;
    constexpr float SCALE = 0.08838834764831845f;  // 1/sqrt(128)

    // ---- load scaled query ----
    for (int i = tid; i < G_ * D_; i += 256) {
        const int g = i >> 7, d = i & 127;
        q_s[g][d] = query[(size_t)b * (H_ * D_) + (size_t)(kh * G_ + g) * D_ + d] * SCALE;
    }
    __syncthreads();

    const float4 q0 = *(const float4*)&q_s[0][dd];
    const float4 q1 = *(const float4*)&q_s[1][dd];
    const float4 q2 = *(const float4*)&q_s[2][dd];
    const float4 q3 = *(const float4*)&q_s[3][dd];

    // wave -> local block of chunk; rows within that block
    const int jl = w >> 1;                    // 0 or 1
    const int j  = ch * CH_ + jl;
    const int tb = b * NB_ + j;
    const int cb = block_list[tb];
    const int sb_base = (w & 1) * 64;
    const float* kb   = kcache + ((size_t)cb * BS_ * HKV + kh) * D_;
    const float* vb   = vcache + ((size_t)cb * BS_ * HKV + kh) * D_;
    const float* brow = block_bias + (size_t)tb * BS_;

    // ---- Phase A: scores ----
#pragma unroll 4
    for (int i = 0; i < 32; ++i) {
        const int sb = sb_base + 2 * i + half;
        const float4 kv = *(const float4*)(kb + (size_t)sb * (HKV * D_) + dd);
        float d0 = kv.x * q0.x + kv.y * q0.y + kv.z * q0.z + kv.w * q0.w;
        float d1 = kv.x * q1.x + kv.y * q1.y + kv.z * q1.z + kv.w * q1.w;
        float d2 = kv.x * q2.x + kv.y * q2.y + kv.z * q2.z + kv.w * q2.w;
        float d3 = kv.x * q3.x + kv.y * q3.y + kv.z * q3.z + kv.w * q3.w;
#pragma unroll
        for (int m = 16; m >= 1; m >>= 1) {
            d0 += __shfl_xor(d0, m, 64);
            d1 += __shfl_xor(d1, m, 64);
            d2 += __shfl_xor(d2, m, 64);
            d3 += __shfl_xor(d3, m, 64);
        }
        if (l5 == 0) {
            const float bv = brow[sb];
            const int p = (w << 6) + 2 * i + half;
            *(float4*)&sc[p][0] = make_float4(d0 + bv, d1 + bv, d2 + bv, d3 + bv);
        }
    }
    __syncthreads();

    // ---- Phase B: local softmax over 256 positions ----
    {
        const int g = tid & 3;
        const int u = tid >> 2;          // 0..63
        float m = -INFINITY;
#pragma unroll
        for (int i = 0; i < 4; ++i) m = fmaxf(m, sc[u + 64 * i][g]);
#pragma unroll
        for (int msk = 4; msk <= 32; msk <<= 1) m = fmaxf(m, __shfl_xor(m, msk, 64));
        if (lane < 4) red[w][lane] = m;
        __syncthreads();
        if (tid < 4)
            mg[tid] = fmaxf(fmaxf(red[0][tid], red[1][tid]),
                            fmaxf(red[2][tid], red[3][tid]));
        __syncthreads();

        const float gmr = mg[g];
        const float gm  = (gmr == -INFINITY) ? 0.f : gmr;  // fully-masked chunk
        float acc = 0.f;
#pragma unroll
        for (int i = 0; i < 4; ++i) {
            const float p = __expf(sc[u + 64 * i][g] - gm);
            sc[u + 64 * i][g] = p;
            acc += p;
        }
#pragma unroll
        for (int msk = 4; msk <= 32; msk <<= 1) acc += __shfl_xor(acc, msk, 64);
        if (lane < 4) red[w][lane] = acc;
        __syncthreads();
        if (tid < 4) dn[tid] = red[0][tid] + red[1][tid] + red[2][tid] + red[3][tid];
        __syncthreads();
    }

    // ---- Phase C: P*V partial ----
    float4 o0 = {0,0,0,0}, o1 = {0,0,0,0}, o2 = {0,0,0,0}, o3 = {0,0,0,0};
#pragma unroll 4
    for (int i = 0; i < 32; ++i) {
        const int sb = sb_base + 2 * i + half;
        const int p  = (w << 6) + 2 * i + half;
        const float4 vv = *(const float4*)(vb + (size_t)sb * (HKV * D_) + dd);
        const float4 pp = *(const float4*)&sc[p][0];   // broadcast per half
        o0.x += pp.x * vv.x; o0.y += pp.x * vv.y; o0.z += pp.x * vv.z; o0.w += pp.x * vv.w;
        o1.x += pp.y * vv.x; o1.y += pp.y * vv.y; o1.z += pp.y * vv.z; o1.w += pp.y * vv.w;
        o2.x += pp.z * vv.x; o2.y += pp.z * vv.y; o2.z += pp.z * vv.z; o2.w += pp.z * vv.w;
        o3.x += pp.w * vv.x; o3.y += pp.w * vv.y; o3.z += pp.w * vv.z; o3.w += pp.w * vv.w;
    }
    // combine the two row-halves (same dims)
    o0.x += __shfl_xor(o0.x, 32, 64); o0.y += __shfl_xor(o0.y, 32, 64);
    o0.z += __shfl_xor(o0.z, 32, 64); o0.w += __shfl_xor(o0.w, 32, 64);
    o1.x += __shfl_xor(o1.x, 32, 64); o1.y += __shfl_xor(o1.y, 32, 64);
    o1.z += __shfl_xor(o1.z, 32, 64); o1.w += __shfl_xor(o1.w, 32, 64);
    o2.x += __shfl_xor(o2.x, 32, 64); o2.y += __shfl_xor(o2.y, 32, 64);
    o2.z += __shfl_xor(o2.z, 32, 64); o2.w += __shfl_xor(o2.w, 32, 64);
    o3.x += __shfl_xor(o3.x, 32, 64); o3.y += __shfl_xor(o3.y, 32, 64);
    o3.z += __shfl_xor(o3.z, 32, 64); o3.w += __shfl_xor(o3.w, 32, 64);
    if (half == 0) {
        *(float4*)&ob[w][0][dd] = o0;
        *(float4*)&ob[w][1][dd] = o1;
        *(float4*)&ob[w][2][dd] = o2;
        *(float4*)&ob[w][3][dd] = o3;
    }
    __syncthreads();

    // ---- write partial (m, l, o) to workspace ----
    float* wp = ws + (size_t)bx * PART_STRIDE;
    if (tid < 4) { wp[tid] = mg[tid]; wp[4 + tid] = dn[tid]; }
    for (int e = tid; e < G_ * D_; e += 256) {
        const int g = e >> 7, d = e & 127;
        wp[8 + e] = ob[0][g][d] + ob[1][g][d] + ob[2][g][d] + ob[3][g][d];
    }
}

// ---------------------------------------------------------------------------
// Kernel 3: combine 8 chunk-partials per (b, kv_head), normalize, store.
// Grid 256, 128 threads (thread = dim).
// ---------------------------------------------------------------------------
__global__ __launch_bounds__(128) void combine_attn(
    const float* __restrict__ ws, float* __restrict__ out)
{
    const int bk = blockIdx.x;          // b*8 + kh
    const int b  = bk >> 3;
    const int kh = bk & 7;
    const int d  = threadIdx.x;
    const float* base = ws + (size_t)bk * NCH * PART_STRIDE;

#pragma unroll
    for (int g = 0; g < G_; ++g) {
        float M = -INFINITY;
#pragma unroll
        for (int c = 0; c < NCH; ++c)
            M = fmaxf(M, base[c * PART_STRIDE + g]);
        float scales[NCH];
        float L = 0.f;
#pragma unroll
        for (int c = 0; c < NCH; ++c) {
            const float mc = base[c * PART_STRIDE + g];
            const float s  = (mc == -INFINITY) ? 0.f : __expf(mc - M);
            scales[c] = s;
            L += s * base[c * PART_STRIDE + 4 + g];
        }
        float o = 0.f;
#pragma unroll
        for (int c = 0; c < NCH; ++c)
            o += scales[c] * base[c * PART_STRIDE + 8 + g * D_ + d];
        out[(size_t)b * (H_ * D_) + (size_t)(kh * G_ + g) * D_ + d] = o / L;
    }
}

extern "C" void kernel_launch(void* const* d_in, const int* in_sizes, int n_in,
                              void* d_out, int out_size, void* d_ws, size_t ws_size,
                              hipStream_t stream) {
    const float* query = (const float*)d_in[0];
    const float* knew  = (const float*)d_in[1];
    const float* vnew  = (const float*)d_in[2];
    float* kcache      = (float*)d_in[3];
    float* vcache      = (float*)d_in[4];
    const int* block_list = (const int*)d_in[5];
    const int* bidx = (const int*)d_in[7];
    const int* boff = (const int*)d_in[8];
    const float* bias = (const float*)d_in[9];
    float* out = (float*)d_out;
    float* ws  = (float*)d_ws;   // needs B*HKV*NCH*520*4 = 4.26 MB

    hipLaunchKernelGGL(scatter_kv, dim3(64), dim3(512), 0, stream,
                       knew, vnew, kcache, vcache, bidx, boff);
    hipLaunchKernelGGL(partial_attn, dim3(B_ * HKV * NCH), dim3(256), 0, stream,
                       query, kcache, vcache, block_list, bias, ws);
    hipLaunchKernelGGL(combine_attn, dim3(B_ * HKV), dim3(128), 0, stream,
                       ws, out);
}

// Round 3
// 576.884 us; speedup vs baseline: 1.3713x; 1.0258x over previous
//
#include <hip/hip_runtime.h>
#include <math.h>

#define B_   32
#define H_   32
#define HKV  8
#define G_   4
#define D_   128
#define BS_  128
#define NB_  16
#define CH_  2             // cache blocks per chunk
#define NCH  (NB_ / CH_)   // 8 chunks per sequence
#define CP_  (CH_ * BS_)   // 256 positions per chunk
#define PART_STRIDE (G_ + G_ + G_ * D_)   // m[4] l[4] o[4][128] = 520 floats

__device__ __forceinline__ float dot4(const float4 a, const float4 b) {
    return a.x * b.x + a.y * b.y + a.z * b.z + a.w * b.w;
}

// ---------------------------------------------------------------------------
// Kernel 1: insert new decode token K/V into the paged caches.
// ---------------------------------------------------------------------------
__global__ __launch_bounds__(512) void scatter_kv(
    const float* __restrict__ knew, const float* __restrict__ vnew,
    float* __restrict__ kcache, float* __restrict__ vcache,
    const int* __restrict__ bidx, const int* __restrict__ boff)
{
    const int gid = blockIdx.x * 512 + threadIdx.x;   // 0..32767
    const int b = gid >> 10;
    const int r = gid & 1023;
    const size_t dst = ((size_t)bidx[b] * BS_ + (size_t)boff[b]) * (HKV * D_) + r;
    kcache[dst] = knew[gid];
    vcache[dst] = vnew[gid];
}

// ---------------------------------------------------------------------------
// Kernel 2: partial attention over one chunk (2 cache blocks = 256 positions)
// of one (b, kv_head). Grid 2048 = B*HKV*NCH, 256 threads (4 waves).
// Wave w owns chunk-local positions [64w, 64w+64).
// Phase A: 8 lanes per K row, 4 float4 loads/lane, 3-level xor reduce.
// Rows at absolute position >= ctx are never loaded (bias is -inf there).
// Fully masked chunks write m=-inf and exit immediately.
// ---------------------------------------------------------------------------
__global__ __launch_bounds__(256) void partial_attn(
    const float* __restrict__ query,
    const float* __restrict__ kcache,
    const float* __restrict__ vcache,
    const int* __restrict__ block_list,
    const float* __restrict__ block_bias,
    const int* __restrict__ bidx, const int* __restrict__ boff,
    float* __restrict__ ws)
{
    __shared__ float q_s[G_][D_];        // 2 KB
    __shared__ float sc[CP_][G_];        // 4 KB scores -> p
    __shared__ float red[4][G_];
    __shared__ float mg[G_];
    __shared__ float dn[G_];
    __shared__ float ob[4][G_][D_];      // 8 KB per-wave o partials

    const int tid  = threadIdx.x;
    const int w    = tid >> 6;
    const int lane = tid & 63;
    const int bx   = blockIdx.x;
    const int ch   = bx & (NCH - 1);
    const int kh   = (bx >> 3) & 7;
    const int b    = bx >> 6;
    constexpr float SCALE = 0.08838834764831845f;  // 1/sqrt(128)

    // ---- recover ctx: which seq-local block holds the new token ----
    const int my_bi = bidx[b];
    int jstar = 0;
#pragma unroll
    for (int jj = 0; jj < NB_; ++jj)
        if (block_list[b * NB_ + jj] == my_bi) jstar = jj;
    const int ctx = jstar * BS_ + boff[b] + 1;   // tokens in this sequence

    float* wp = ws + (size_t)bx * PART_STRIDE;
    const int chunk_start = ch * CP_;
    if (ctx <= chunk_start) {                    // fully masked chunk
        if (tid < 4) wp[tid] = -INFINITY;        // combine scales by 0
        return;
    }

    // ---- load scaled query; init scores to -inf ----
    for (int i = tid; i < G_ * D_; i += 256) {
        const int g = i >> 7, d = i & 127;
        q_s[g][d] = query[(size_t)b * (H_ * D_) + (size_t)(kh * G_ + g) * D_ + d] * SCALE;
    }
    *(float4*)&sc[tid][0] = make_float4(-INFINITY, -INFINITY, -INFINITY, -INFINITY);
    __syncthreads();

    // wave -> block and 64-row window
    const int jl = w >> 1;
    const int j  = ch * CH_ + jl;
    const int tb = b * NB_ + j;
    const int cb = block_list[tb];
    const int sb_base = (w & 1) * 64;
    const float* kb   = kcache + ((size_t)cb * BS_ * HKV + kh) * D_;
    const float* vb   = vcache + ((size_t)cb * BS_ * HKV + kh) * D_;
    const float* brow = block_bias + (size_t)tb * BS_;

    const int wave_start = j * BS_ + sb_base;                 // abs pos of row 0
    const int valid_rows = min(64, max(0, ctx - wave_start)); // rows to process

    // ---- Phase A: scores (8 lanes per row, 3-level reduce) ----
    {
        const int l3 = lane >> 3;    // row subgroup 0..7
        const int l8 = lane & 7;     // dim subgroup
        const int doff = l8 * 4;
        const float4 q00 = *(const float4*)&q_s[0][doff];
        const float4 q01 = *(const float4*)&q_s[0][32 + doff];
        const float4 q02 = *(const float4*)&q_s[0][64 + doff];
        const float4 q03 = *(const float4*)&q_s[0][96 + doff];
        const float4 q10 = *(const float4*)&q_s[1][doff];
        const float4 q11 = *(const float4*)&q_s[1][32 + doff];
        const float4 q12 = *(const float4*)&q_s[1][64 + doff];
        const float4 q13 = *(const float4*)&q_s[1][96 + doff];
        const float4 q20 = *(const float4*)&q_s[2][doff];
        const float4 q21 = *(const float4*)&q_s[2][32 + doff];
        const float4 q22 = *(const float4*)&q_s[2][64 + doff];
        const float4 q23 = *(const float4*)&q_s[2][96 + doff];
        const float4 q30 = *(const float4*)&q_s[3][doff];
        const float4 q31 = *(const float4*)&q_s[3][32 + doff];
        const float4 q32 = *(const float4*)&q_s[3][64 + doff];
        const float4 q33 = *(const float4*)&q_s[3][96 + doff];

        const int itA = (valid_rows + 7) >> 3;
        for (int i = 0; i < itA; ++i) {
            const int r  = (i << 3) + l3;
            const int sb = sb_base + r;
            const bool act = r < valid_rows;
            float4 k0 = {0,0,0,0}, k1 = {0,0,0,0}, k2 = {0,0,0,0}, k3 = {0,0,0,0};
            const float* kr = kb + (size_t)sb * (HKV * D_) + doff;
            if (act) {
                k0 = *(const float4*)(kr);
                k1 = *(const float4*)(kr + 32);
                k2 = *(const float4*)(kr + 64);
                k3 = *(const float4*)(kr + 96);
            }
            float d0 = dot4(k0,q00) + dot4(k1,q01) + dot4(k2,q02) + dot4(k3,q03);
            float d1 = dot4(k0,q10) + dot4(k1,q11) + dot4(k2,q12) + dot4(k3,q13);
            float d2 = dot4(k0,q20) + dot4(k1,q21) + dot4(k2,q22) + dot4(k3,q23);
            float d3 = dot4(k0,q30) + dot4(k1,q31) + dot4(k2,q32) + dot4(k3,q33);
#pragma unroll
            for (int m = 4; m >= 1; m >>= 1) {
                d0 += __shfl_xor(d0, m, 64);
                d1 += __shfl_xor(d1, m, 64);
                d2 += __shfl_xor(d2, m, 64);
                d3 += __shfl_xor(d3, m, 64);
            }
            if (l8 == 0) {
                const float bv = act ? brow[sb] : -INFINITY;
                *(float4*)&sc[(w << 6) + r][0] =
                    make_float4(d0 + bv, d1 + bv, d2 + bv, d3 + bv);
            }
        }
    }
    __syncthreads();

    // ---- Phase B: local softmax over 256 positions ----
    {
        const int g = tid & 3;
        const int u = tid >> 2;
        float m = -INFINITY;
#pragma unroll
        for (int i = 0; i < 4; ++i) m = fmaxf(m, sc[u + 64 * i][g]);
#pragma unroll
        for (int msk = 4; msk <= 32; msk <<= 1) m = fmaxf(m, __shfl_xor(m, msk, 64));
        if (lane < 4) red[w][lane] = m;
        __syncthreads();
        if (tid < 4)
            mg[tid] = fmaxf(fmaxf(red[0][tid], red[1][tid]),
                            fmaxf(red[2][tid], red[3][tid]));
        __syncthreads();

        const float gmr = mg[g];
        const float gm  = (gmr == -INFINITY) ? 0.f : gmr;
        float acc = 0.f;
#pragma unroll
        for (int i = 0; i < 4; ++i) {
            const float p = __expf(sc[u + 64 * i][g] - gm);
            sc[u + 64 * i][g] = p;
            acc += p;
        }
#pragma unroll
        for (int msk = 4; msk <= 32; msk <<= 1) acc += __shfl_xor(acc, msk, 64);
        if (lane < 4) red[w][lane] = acc;
        __syncthreads();
        if (tid < 4) dn[tid] = red[0][tid] + red[1][tid] + red[2][tid] + red[3][tid];
        __syncthreads();
    }

    // ---- Phase C: P*V partial (2 rows per iter via lane halves) ----
    {
        const int half = lane >> 5;
        const int l5   = lane & 31;
        const int dd   = l5 * 4;
        float4 o0 = {0,0,0,0}, o1 = {0,0,0,0}, o2 = {0,0,0,0}, o3 = {0,0,0,0};
        const int itC = min(32, (valid_rows + 1) >> 1);
        for (int i = 0; i < itC; ++i) {
            const int r  = 2 * i + half;   // boundary overshoot ok: p = 0
            const int sb = sb_base + r;
            const float4 vv = *(const float4*)(vb + (size_t)sb * (HKV * D_) + dd);
            const float4 pp = *(const float4*)&sc[(w << 6) + r][0];
            o0.x += pp.x * vv.x; o0.y += pp.x * vv.y; o0.z += pp.x * vv.z; o0.w += pp.x * vv.w;
            o1.x += pp.y * vv.x; o1.y += pp.y * vv.y; o1.z += pp.y * vv.z; o1.w += pp.y * vv.w;
            o2.x += pp.z * vv.x; o2.y += pp.z * vv.y; o2.z += pp.z * vv.z; o2.w += pp.z * vv.w;
            o3.x += pp.w * vv.x; o3.y += pp.w * vv.y; o3.z += pp.w * vv.z; o3.w += pp.w * vv.w;
        }
        o0.x += __shfl_xor(o0.x, 32, 64); o0.y += __shfl_xor(o0.y, 32, 64);
        o0.z += __shfl_xor(o0.z, 32, 64); o0.w += __shfl_xor(o0.w, 32, 64);
        o1.x += __shfl_xor(o1.x, 32, 64); o1.y += __shfl_xor(o1.y, 32, 64);
        o1.z += __shfl_xor(o1.z, 32, 64); o1.w += __shfl_xor(o1.w, 32, 64);
        o2.x += __shfl_xor(o2.x, 32, 64); o2.y += __shfl_xor(o2.y, 32, 64);
        o2.z += __shfl_xor(o2.z, 32, 64); o2.w += __shfl_xor(o2.w, 32, 64);
        o3.x += __shfl_xor(o3.x, 32, 64); o3.y += __shfl_xor(o3.y, 32, 64);
        o3.z += __shfl_xor(o3.z, 32, 64); o3.w += __shfl_xor(o3.w, 32, 64);
        if (half == 0) {
            *(float4*)&ob[w][0][dd] = o0;
            *(float4*)&ob[w][1][dd] = o1;
            *(float4*)&ob[w][2][dd] = o2;
            *(float4*)&ob[w][3][dd] = o3;
        }
    }
    __syncthreads();

    // ---- write partial (m, l, o) ----
    if (tid < 4) { wp[tid] = mg[tid]; wp[4 + tid] = dn[tid]; }
    for (int e = tid; e < G_ * D_; e += 256) {
        const int g = e >> 7, d = e & 127;
        wp[8 + e] = ob[0][g][d] + ob[1][g][d] + ob[2][g][d] + ob[3][g][d];
    }
}

// ---------------------------------------------------------------------------
// Kernel 3: combine 8 chunk-partials per (b, kv_head), normalize, store.
// ---------------------------------------------------------------------------
__global__ __launch_bounds__(128) void combine_attn(
    const float* __restrict__ ws, float* __restrict__ out)
{
    const int bk = blockIdx.x;
    const int b  = bk >> 3;
    const int kh = bk & 7;
    const int d  = threadIdx.x;
    const float* base = ws + (size_t)bk * NCH * PART_STRIDE;

#pragma unroll
    for (int g = 0; g < G_; ++g) {
        float M = -INFINITY;
#pragma unroll
        for (int c = 0; c < NCH; ++c)
            M = fmaxf(M, base[c * PART_STRIDE + g]);
        float scales[NCH];
        float L = 0.f;
#pragma unroll
        for (int c = 0; c < NCH; ++c) {
            const float mc = base[c * PART_STRIDE + g];
            const float s  = (mc == -INFINITY) ? 0.f : __expf(mc - M);
            scales[c] = s;
            L += s * base[c * PART_STRIDE + 4 + g];
        }
        float o = 0.f;
#pragma unroll
        for (int c = 0; c < NCH; ++c)
            o += scales[c] * base[c * PART_STRIDE + 8 + g * D_ + d];
        out[(size_t)b * (H_ * D_) + (size_t)(kh * G_ + g) * D_ + d] = o / L;
    }
}

extern "C" void kernel_launch(void* const* d_in, const int* in_sizes, int n_in,
                              void* d_out, int out_size, void* d_ws, size_t ws_size,
                              hipStream_t stream) {
    const float* query = (const float*)d_in[0];
    const float* knew  = (const float*)d_in[1];
    const float* vnew  = (const float*)d_in[2];
    float* kcache      = (float*)d_in[3];
    float* vcache      = (float*)d_in[4];
    const int* block_list = (const int*)d_in[5];
    const int* bidx = (const int*)d_in[7];
    const int* boff = (const int*)d_in[8];
    const float* bias = (const float*)d_in[9];
    float* out = (float*)d_out;
    float* ws  = (float*)d_ws;   // needs B*HKV*NCH*520*4 = 4.26 MB

    hipLaunchKernelGGL(scatter_kv, dim3(64), dim3(512), 0, stream,
                       knew, vnew, kcache, vcache, bidx, boff);
    hipLaunchKernelGGL(partial_attn, dim3(B_ * HKV * NCH), dim3(256), 0, stream,
                       query, kcache, vcache, block_list, bias, bidx, boff, ws);
    hipLaunchKernelGGL(combine_attn, dim3(B_ * HKV), dim3(128), 0, stream,
                       ws, out);
}